// Round 3
// baseline (154.607 us; speedup 1.0000x reference)
//
#include <hip/hip_runtime.h>
#include <hip/hip_bf16.h>

#define K_NEIGH  10
#define D_DIM    256
#define SLICE_F  16          // floats per column slice = 64 B = 1 cache line
#define NSLICE   16          // 256 / 16
#define NXCD     8
#define NODES_PER_BLOCK 64   // 4 waves x 16 nodes

typedef float f32x4 __attribute__((ext_vector_type(4)));

// Column-sliced gather-mean: XCD x (bid%8 under round-robin dispatch) owns
// column slices {x, x+8}. Active working set per XCD L2 = 50000 rows x 64 B
// = 3.2 MB < 4 MB, so gathers become L2 hits after the compulsory pass.
__global__ __launch_bounds__(256) void mean_agg_slice_kernel(
    const int* __restrict__ idx,          // [N, 10] int32
    const float* __restrict__ embed,      // [M, 256] f32
    float* __restrict__ out,              // [N, 256] f32
    int n_nodes, int blocks_per_slice)
{
    const int bid = blockIdx.x;
    const int x   = bid & (NXCD - 1);         // XCD under round-robin dispatch
    const int t   = bid >> 3;
    const int r   = t / blocks_per_slice;     // slice round: 0 or 1
    const int c   = t - r * blocks_per_slice; // node-chunk within round
    const int s   = r * NXCD + x;             // slice id 0..15

    const int wave = threadIdx.x >> 6;
    const int lane = threadIdx.x & 63;
    const int nl   = lane >> 2;               // node within wave: 0..15
    const int q    = lane & 3;                // float4 within the 64B slice

    const int node = c * NODES_PER_BLOCK + wave * 16 + nl;
    if (node >= n_nodes) return;

    // 10 neighbor ids for this node (quad-uniform addresses; the 640 B/wave
    // window stays hot in L1 across the 10 loads)
    const int* nidx = idx + (size_t)node * K_NEIGH;
    const int r0 = nidx[0], r1 = nidx[1], r2 = nidx[2], r3 = nidx[3],
              r4 = nidx[4], r5 = nidx[5], r6 = nidx[6], r7 = nidx[7],
              r8 = nidx[8], r9 = nidx[9];

    // Gather this slice (64 B) of each neighbor row; all 10 in flight.
    const float* eb = embed + (size_t)s * SLICE_F;
    f32x4 v0 = ((const f32x4*)(eb + (size_t)r0 * D_DIM))[q];
    f32x4 v1 = ((const f32x4*)(eb + (size_t)r1 * D_DIM))[q];
    f32x4 v2 = ((const f32x4*)(eb + (size_t)r2 * D_DIM))[q];
    f32x4 v3 = ((const f32x4*)(eb + (size_t)r3 * D_DIM))[q];
    f32x4 v4 = ((const f32x4*)(eb + (size_t)r4 * D_DIM))[q];
    f32x4 v5 = ((const f32x4*)(eb + (size_t)r5 * D_DIM))[q];
    f32x4 v6 = ((const f32x4*)(eb + (size_t)r6 * D_DIM))[q];
    f32x4 v7 = ((const f32x4*)(eb + (size_t)r7 * D_DIM))[q];
    f32x4 v8 = ((const f32x4*)(eb + (size_t)r8 * D_DIM))[q];
    f32x4 v9 = ((const f32x4*)(eb + (size_t)r9 * D_DIM))[q];

    f32x4 acc = (((v0 + v1) + (v2 + v3)) + ((v4 + v5) + (v6 + v7))) + (v8 + v9);
    acc *= 0.1f;

    // Full-line (64 B per node) streaming store; nontemporal to keep the
    // write stream from evicting the resident embed slice.
    __builtin_nontemporal_store(
        acc, (f32x4*)(out + (size_t)node * D_DIM + (size_t)s * SLICE_F) + q);
}

extern "C" void kernel_launch(void* const* d_in, const int* in_sizes, int n_in,
                              void* d_out, int out_size, void* d_ws, size_t ws_size,
                              hipStream_t stream) {
    const int*   idx   = (const int*)d_in[0];     // neighbor_idx [N,10]
    const float* embed = (const float*)d_in[1];   // embed_matrix [M,256]
    float*       out   = (float*)d_out;           // [N,256]

    const int n_nodes = in_sizes[0] / K_NEIGH;    // 100000
    const int blocks_per_slice = (n_nodes + NODES_PER_BLOCK - 1) / NODES_PER_BLOCK;
    // 2 rounds x 8 XCD-interleaved slice-blocks
    const int grid = 2 * NXCD * blocks_per_slice;

    mean_agg_slice_kernel<<<grid, 256, 0, stream>>>(idx, embed, out,
                                                    n_nodes, blocks_per_slice);
}